// Round 1
// baseline (626.457 us; speedup 1.0000x reference)
//
#include <hip/hip_runtime.h>
#include <hip/hip_bf16.h>
#include <math.h>

#define BB 32
#define TT 4096
#define DD 256
#define LL 2
#define NC 64          // number of time chunks for the scan
#define CH 64          // chunk length (NC*CH == TT)
#define MM (BB*TT)     // 131072 rows
#define EPSV 1e-5f

typedef __bf16 bf16;
typedef __attribute__((ext_vector_type(8))) __bf16 bf16x8;
typedef __attribute__((ext_vector_type(4))) __bf16 bf16x4;
typedef __attribute__((ext_vector_type(4))) float f32x4;

// ---------------------------------------------------------------------------
// decay[d] = exp(-1/tau), tau = exp(linspace(log 10, log 2000, 256))
__device__ __forceinline__ float decay_of(int d) {
    const float l0 = 2.302585092994046f;      // log(10)
    const float l1 = 7.6009024595420815f;     // log(2000)
    float lt = l0 + (float)d * (l1 - l0) * (1.0f / 255.0f);
    return expf(-expf(-lt));
}

__device__ __forceinline__ float silu_f(float v) {
    return v / (1.0f + expf(-v));
}

// ---------------------------------------------------------------------------
// fp32 -> bf16 weight conversion
__global__ void cvtw_k(const float* __restrict__ s, bf16* __restrict__ d, int n) {
    int i = blockIdx.x * 256 + threadIdx.x;
    if (i < n) d[i] = (bf16)s[i];
}

// ---------------------------------------------------------------------------
// GEMM: C[M x 256cols-per-blockIdx.y] = A[M x 256] * W[N x 256]^T + bias
// A row-major (lda elems), W row-major (N x K=256) bf16.
// EPI: 0 = store bf16; 1 = rowwise LayerNorm(256) + ReLU, store bf16 (needs gridDim.y==1);
//      2 = residual: Cout[o] += acc (in-place bf16)
// block: 512 threads (8 waves), each wave computes 16 rows x 256 cols.
template<int SRCF32, int EPI>
__global__ __launch_bounds__(512, 1)
void gemm_k(const void* __restrict__ Asrc, int lda,
            const bf16* __restrict__ W,
            const float* __restrict__ bias,
            const float* __restrict__ lng, const float* __restrict__ lnb,
            bf16* __restrict__ Cout, int ldc)
{
    __shared__ char lds[131072];   // 256 cols x 256 K x 2B, XOR-swizzled
    const int tid = threadIdx.x;
    const int colblk = blockIdx.y * 256;
    const bf16* Wblk = W + (size_t)colblk * 256;

    // stage W tile into LDS (swizzled: 16B slot index XORed with (row&7))
    #pragma unroll
    for (int i = 0; i < 16; ++i) {
        int idx = tid + i * 512;
        int n  = idx >> 5;          // col (0..255)
        int kc = idx & 31;          // 16B chunk within 512B row
        *(bf16x8*)(&lds[n * 512 + ((kc * 16) ^ ((n & 7) << 4))]) =
            *(const bf16x8*)(Wblk + n * 256 + kc * 8);
    }
    __syncthreads();

    const int wave = tid >> 6, lane = tid & 63;
    const int r = lane & 15, g4 = lane >> 4;
    const size_t row0 = (size_t)blockIdx.x * 128 + wave * 16;

    f32x4 acc[16];
    #pragma unroll
    for (int nt = 0; nt < 16; ++nt) {
        float bv = bias[colblk + nt * 16 + r];
        acc[nt] = (f32x4){bv, bv, bv, bv};
    }

    // prefetch all 8 A fragments (row = row0+r, k = kk*32 + g4*8 .. +7)
    bf16x8 af[8];
    if (SRCF32) {
        const float* A = (const float*)Asrc;
        #pragma unroll
        for (int kk = 0; kk < 8; ++kk) {
            const float* ap = A + (row0 + r) * (size_t)lda + kk * 32 + g4 * 8;
            float4 f0 = *(const float4*)ap;
            float4 f1 = *(const float4*)(ap + 4);
            bf16x8 t;
            t[0]=(bf16)f0.x; t[1]=(bf16)f0.y; t[2]=(bf16)f0.z; t[3]=(bf16)f0.w;
            t[4]=(bf16)f1.x; t[5]=(bf16)f1.y; t[6]=(bf16)f1.z; t[7]=(bf16)f1.w;
            af[kk] = t;
        }
    } else {
        const bf16* A = (const bf16*)Asrc;
        #pragma unroll
        for (int kk = 0; kk < 8; ++kk)
            af[kk] = *(const bf16x8*)(A + (row0 + r) * (size_t)lda + kk * 32 + g4 * 8);
    }

    #pragma unroll
    for (int kk = 0; kk < 8; ++kk) {
        const int kb = kk * 64 + g4 * 16;   // byte offset of this lane-group's k in a W row
        #pragma unroll
        for (int nt = 0; nt < 16; ++nt) {
            int col = nt * 16 + r;
            bf16x8 bfr = *(const bf16x8*)(&lds[col * 512 + (kb ^ ((col & 7) << 4))]);
            acc[nt] = __builtin_amdgcn_mfma_f32_16x16x32_bf16(af[kk], bfr, acc[nt], 0, 0, 0);
        }
    }

    // epilogue  (C/D layout: col = lane&15, row = (lane>>4)*4 + i)
    if (EPI == 1) {
        float s[4], q[4];
        #pragma unroll
        for (int i = 0; i < 4; ++i) { s[i] = 0.f; q[i] = 0.f; }
        #pragma unroll
        for (int nt = 0; nt < 16; ++nt)
            #pragma unroll
            for (int i = 0; i < 4; ++i) { float v = acc[nt][i]; s[i] += v; q[i] += v * v; }
        #pragma unroll
        for (int m = 1; m < 16; m <<= 1)
            #pragma unroll
            for (int i = 0; i < 4; ++i) { s[i] += __shfl_xor(s[i], m); q[i] += __shfl_xor(q[i], m); }
        float mean[4], rstd[4];
        #pragma unroll
        for (int i = 0; i < 4; ++i) {
            mean[i] = s[i] * (1.0f / 256.0f);
            float var = q[i] * (1.0f / 256.0f) - mean[i] * mean[i];
            rstd[i] = rsqrtf(var + EPSV);
        }
        #pragma unroll
        for (int nt = 0; nt < 16; ++nt) {
            int col = nt * 16 + r;
            float gg = lng[col], bb = lnb[col];
            #pragma unroll
            for (int i = 0; i < 4; ++i) {
                float v = (acc[nt][i] - mean[i]) * rstd[i] * gg + bb;
                v = fmaxf(v, 0.0f);
                Cout[(row0 + g4 * 4 + i) * (size_t)ldc + col] = (bf16)v;
            }
        }
    } else if (EPI == 2) {
        #pragma unroll
        for (int nt = 0; nt < 16; ++nt)
            #pragma unroll
            for (int i = 0; i < 4; ++i) {
                size_t o = (row0 + g4 * 4 + i) * (size_t)ldc + colblk + nt * 16 + r;
                Cout[o] = (bf16)(acc[nt][i] + (float)Cout[o]);
            }
    } else {
        #pragma unroll
        for (int nt = 0; nt < 16; ++nt)
            #pragma unroll
            for (int i = 0; i < 4; ++i)
                Cout[(row0 + g4 * 4 + i) * (size_t)ldc + colblk + nt * 16 + r] = (bf16)acc[nt][i];
    }
}

// ---------------------------------------------------------------------------
// pass 1: causal conv(K=4) + SiLU + local EMA scan within a 64-step chunk.
// xz layout: (B, T, 512) bf16, x_in = cols [0,256). hlocal: (B,T,256) fp32 (in d_out).
__global__ void conv_scan1_k(const bf16* __restrict__ xz,
                             const float* __restrict__ cw, const float* __restrict__ cb,
                             float* __restrict__ hlocal, float* __restrict__ cfin)
{
    const int d = threadIdx.x, c = blockIdx.x, b = blockIdx.y;
    const float w0 = cw[d * 4 + 0], w1 = cw[d * 4 + 1], w2 = cw[d * 4 + 2], w3 = cw[d * 4 + 3];
    const float bb = cb[d];
    const float a = decay_of(d);
    const int t0 = c * CH;
    const size_t base  = (size_t)b * TT * 512 + d;
    const size_t obase = (size_t)b * TT * 256 + d;
    float xm1 = 0.f, xm2 = 0.f, xm3 = 0.f;
    if (t0 >= 1) xm1 = (float)xz[base + (size_t)(t0 - 1) * 512];
    if (t0 >= 2) xm2 = (float)xz[base + (size_t)(t0 - 2) * 512];
    if (t0 >= 3) xm3 = (float)xz[base + (size_t)(t0 - 3) * 512];
    float hl = 0.f;
    for (int t = t0; t < t0 + CH; ++t) {
        float xc = (float)xz[base + (size_t)t * 512];
        float v = w3 * xc + w2 * xm1 + w1 * xm2 + w0 * xm3 + bb;
        float co = silu_f(v);
        hl = a * hl + (1.0f - a) * co;
        hlocal[obase + (size_t)t * 256] = hl;
        xm3 = xm2; xm2 = xm1; xm1 = xc;
    }
    cfin[((size_t)b * NC + c) * 256 + d] = hl;
}

// pass 2: per-(b,d) carry recurrence over the 64 chunk finals.
__global__ void scan2_k(const float* __restrict__ cfin, float* __restrict__ cin)
{
    const int d = threadIdx.x, b = blockIdx.x;
    float a = decay_of(d);
    float aC = a;
    #pragma unroll
    for (int j = 0; j < 6; ++j) aC *= aC;   // a^64
    float H = 0.f;
    for (int c = 0; c < NC; ++c) {
        size_t o = ((size_t)b * NC + c) * 256 + d;
        cin[o] = H;
        H = aC * H + cfin[o];
    }
}

// pass 3: hi = hlocal + a^(t-t0+1)*carry;  u = hi * silu(z); overwrite x-half of xz with u.
__global__ void pass3_k(const float* __restrict__ hlocal, const float* __restrict__ cin,
                        bf16* __restrict__ xz)
{
    const int d = threadIdx.x, c = blockIdx.x, b = blockIdx.y;
    const float a = decay_of(d);
    float carry = cin[((size_t)b * NC + c) * 256 + d];
    float ap = a;
    const int t0 = c * CH;
    const size_t hbase = (size_t)b * TT * 256 + d;
    const size_t zbase = (size_t)b * TT * 512 + d;
    for (int t = t0; t < t0 + CH; ++t) {
        float hi = hlocal[hbase + (size_t)t * 256] + ap * carry;
        ap *= a;
        float z = (float)xz[zbase + (size_t)t * 512 + 256];
        xz[zbase + (size_t)t * 512] = (bf16)(hi * silu_f(z));
    }
}

// ---------------------------------------------------------------------------
// final LayerNorm: one wave per row of 256, fp32 out.
__global__ __launch_bounds__(256)
void final_ln_k(const bf16* __restrict__ h, const float* __restrict__ g,
                const float* __restrict__ b2, float* __restrict__ out)
{
    const int wave = threadIdx.x >> 6, lane = threadIdx.x & 63;
    const size_t row = (size_t)blockIdx.x * 4 + wave;
    bf16x4 v4 = *(const bf16x4*)(h + row * 256 + lane * 4);
    float v[4];
    #pragma unroll
    for (int j = 0; j < 4; ++j) v[j] = (float)v4[j];
    float s = v[0] + v[1] + v[2] + v[3];
    float q = v[0]*v[0] + v[1]*v[1] + v[2]*v[2] + v[3]*v[3];
    #pragma unroll
    for (int m = 1; m < 64; m <<= 1) { s += __shfl_xor(s, m); q += __shfl_xor(q, m); }
    float mean = s * (1.0f / 256.0f);
    float var  = q * (1.0f / 256.0f) - mean * mean;
    float rstd = rsqrtf(var + EPSV);
    int cb = lane * 4;
    float4 o;
    o.x = (v[0] - mean) * rstd * g[cb + 0] + b2[cb + 0];
    o.y = (v[1] - mean) * rstd * g[cb + 1] + b2[cb + 1];
    o.z = (v[2] - mean) * rstd * g[cb + 2] + b2[cb + 2];
    o.w = (v[3] - mean) * rstd * g[cb + 3] + b2[cb + 3];
    *(float4*)(out + row * 256 + cb) = o;
}

// ---------------------------------------------------------------------------
extern "C" void kernel_launch(void* const* d_in, const int* in_sizes, int n_in,
                              void* d_out, int out_size, void* d_ws, size_t ws_size,
                              hipStream_t stream)
{
    (void)in_sizes; (void)n_in; (void)out_size;
    const float* x        = (const float*)d_in[0];
    const float* enc_w    = (const float*)d_in[1];
    const float* enc_b    = (const float*)d_in[2];
    const float* enc_ln_g = (const float*)d_in[3];
    const float* enc_ln_b = (const float*)d_in[4];
    const float* in_proj_w  = (const float*)d_in[5];
    const float* in_proj_b  = (const float*)d_in[6];
    const float* conv_w     = (const float*)d_in[7];
    const float* conv_b     = (const float*)d_in[8];
    const float* out_proj_w = (const float*)d_in[9];
    const float* out_proj_b = (const float*)d_in[10];
    const float* lnf_g      = (const float*)d_in[11];
    const float* lnf_b      = (const float*)d_in[12];

    // workspace layout (bytes):
    //   h     : 67,108,864   (B*T*256 bf16)
    //   xz    : 134,217,728  (B*T*512 bf16)
    //   wenc  : 131,072      inproj: 524,288   outproj: 262,144  (bf16 weights)
    //   cfin  : 2,097,152    cin: 2,097,152    (scan carries, fp32)
    if (ws_size < 206438400u) return;
    char* ws = (char*)d_ws;
    bf16*  h     = (bf16*)(ws);
    bf16*  xz    = (bf16*)(ws + 67108864);
    bf16*  wenc  = (bf16*)(ws + 201326592);
    bf16*  winp  = (bf16*)(ws + 201457664);
    bf16*  woutp = (bf16*)(ws + 201981952);
    float* cfin  = (float*)(ws + 202244096);
    float* cin   = (float*)(ws + 204341248);
    float* hlocal = (float*)d_out;   // (B,T,256) fp32 scratch; overwritten by final LN

    cvtw_k<<<dim3(256),  dim3(256), 0, stream>>>(enc_w,      wenc,  65536);
    cvtw_k<<<dim3(1024), dim3(256), 0, stream>>>(in_proj_w,  winp,  262144);
    cvtw_k<<<dim3(512),  dim3(256), 0, stream>>>(out_proj_w, woutp, 131072);

    dim3 gblk(512);
    // encoder: h = relu(LN(x @ enc_w^T + enc_b))
    gemm_k<1, 1><<<dim3(1024, 1), gblk, 0, stream>>>(x, 256, wenc, enc_b,
                                                     enc_ln_g, enc_ln_b, h, 256);
    for (int l = 0; l < LL; ++l) {
        // xz = h @ in_proj_w[l]^T + b   (N = 512, two column groups)
        gemm_k<0, 0><<<dim3(1024, 2), gblk, 0, stream>>>(h, 256, winp + (size_t)l * 512 * 256,
                                                         in_proj_b + l * 512, nullptr, nullptr,
                                                         xz, 512);
        conv_scan1_k<<<dim3(NC, BB), dim3(256), 0, stream>>>(xz, conv_w + l * DD * 4,
                                                             conv_b + l * DD, hlocal, cfin);
        scan2_k<<<dim3(BB), dim3(256), 0, stream>>>(cfin, cin);
        pass3_k<<<dim3(NC, BB), dim3(256), 0, stream>>>(hlocal, cin, xz);
        // h += u @ out_proj_w[l]^T + b
        gemm_k<0, 2><<<dim3(1024, 1), gblk, 0, stream>>>(xz, 512, woutp + (size_t)l * 256 * 256,
                                                         out_proj_b + l * 256, nullptr, nullptr,
                                                         h, 256);
    }
    final_ln_k<<<dim3(MM / 4), dim3(256), 0, stream>>>(h, lnf_g, lnf_b, (float*)d_out);
}